// Round 10
// baseline (229.838 us; speedup 1.0000x reference)
//
#include <hip/hip_runtime.h>
#include <hip/hip_cooperative_groups.h>
#include <cstdint>

namespace cg = cooperative_groups;

#define D 128
#define K 1024
#define NB 4096
#define BB 8     // rows per block in mode/loss phase
#define TK 64    // centroid rows per LDS tile (tier-2 fallback)
#define FEPS 1e-6f

typedef unsigned long long u64;
typedef unsigned int u32;
typedef unsigned short u16;

// ============================================================================
// ws layout (byte offsets), total 4,066,816 B:
//   sval     @0        [D][K] f32   512KB  sorted column values
//   xT       @524288   [D][NB] f32  2MB    transposed x
//   ext      @2621440  4*D f32/int  2KB    col min/max val + first idx
//   meta     @2623488  [D][2] f32   1KB    (vmin, scale) per column
//   binstart @2624512  [D][257] u32 128KB  bin starts + sentinel
//   shead    @2756096  [D][K] u16   256KB  run-head original index
//   iminT    @3018240  [D][NB] u16  1MB    per-(d,b) argmin index
// ============================================================================

__device__ __forceinline__ int vbin(float v, float vmin, float scale) {
    float fb = (v - vmin) * scale;
    fb = fminf(fmaxf(fb, 0.0f), 255.0f);
    return (int)fb;
}

struct SMemA {                 // phase A (sort): 25.4 KB
    u64 bkeys[K];
    u64 skeys[K];
    float svs[K];
    u16 shs[K];
    u32 binstart[257];
    u32 pfx[256];
    u32 cursor[256];
    float red[8];
};
struct SMemB {                 // phase B (search): 7.1 KB
    float svs[K];
    u16 shs[K];
    u32 binstart[257];
};
struct SMemC {                 // phase C (mode+loss): 20.1 KB
    float xs[BB * D];
    u32 cntA[BB * K / 4];
    u32 cntB[BB * K / 4];
    int modes[2 * BB];
};
union SMem { SMemA a; SMemB b; SMemC c; };

// ---------------------------------------------------------------------------
// Fused cooperative kernel: 512 blocks x 256 threads, 2 grid syncs.
// ---------------------------------------------------------------------------
__global__ __launch_bounds__(256, 2) void fused_kernel(
    const float* __restrict__ cen, const float* __restrict__ x,
    float* __restrict__ sval, u16* __restrict__ shead,
    u32* __restrict__ binstartG, float* __restrict__ meta,
    float* __restrict__ ext, float* __restrict__ xT,
    u16* __restrict__ iminT, float* __restrict__ out)
{
    cg::grid_group grid = cg::this_grid();
    __shared__ SMem sm;

    const int bid = blockIdx.x;
    const int t = threadIdx.x;

    // ======================= Phase A ====================================
    if (bid < D) {
        // ---- bin-rank sort of column `bid` (verified round-9 semantics) ----
        const int dcol = bid;
        const int wave = t >> 6, lane = t & 63;
        if (dcol == 0 && t == 0) out[0] = 0.0f;

        float v[4];
        #pragma unroll
        for (int j = 0; j < 4; ++j) v[j] = cen[(j * 256 + t) * D + dcol];

        float mn = fminf(fminf(v[0], v[1]), fminf(v[2], v[3]));
        float mx = fmaxf(fmaxf(v[0], v[1]), fmaxf(v[2], v[3]));
        #pragma unroll
        for (int s = 32; s >= 1; s >>= 1) {
            mn = fminf(mn, __shfl_xor(mn, s, 64));
            mx = fmaxf(mx, __shfl_xor(mx, s, 64));
        }
        if (lane == 0) { sm.a.red[wave] = mn; sm.a.red[4 + wave] = mx; }
        sm.a.binstart[t] = 0u;               // histogram init
        if (t == 0) sm.a.binstart[256] = 0u;
        __syncthreads();

        const float vmin = fminf(fminf(sm.a.red[0], sm.a.red[1]),
                                 fminf(sm.a.red[2], sm.a.red[3]));
        const float vmax = fmaxf(fmaxf(sm.a.red[4], sm.a.red[5]),
                                 fmaxf(sm.a.red[6], sm.a.red[7]));
        const float range = vmax - vmin;
        const float scale = (range > 0.0f) ? (255.0f / range) : 0.0f;

        u64 key[4]; int bk[4];
        #pragma unroll
        for (int j = 0; j < 4; ++j) {
            u32 u = __float_as_uint(v[j]);
            u = (u & 0x80000000u) ? ~u : (u | 0x80000000u);   // monotone map
            key[j] = ((u64)u << 32) | (u32)(j * 256 + t);
            bk[j] = vbin(v[j], vmin, scale);
            atomicAdd(&sm.a.binstart[bk[j]], 1u);
        }
        __syncthreads();

        // exclusive prefix over 256 bins (Hillis-Steele on inclusive)
        u32 myh = sm.a.binstart[t];
        sm.a.pfx[t] = myh;
        __syncthreads();
        #pragma unroll
        for (int s = 1; s < 256; s <<= 1) {
            u32 add = (t >= s) ? sm.a.pfx[t - s] : 0u;
            __syncthreads();
            sm.a.pfx[t] += add;
            __syncthreads();
        }
        {
            u32 st = sm.a.pfx[t] - myh;
            sm.a.binstart[t] = st;
            sm.a.cursor[t] = st;
            if (t == 0) sm.a.binstart[256] = K;
        }
        __syncthreads();

        // scatter by bin
        #pragma unroll
        for (int j = 0; j < 4; ++j) {
            u32 s = atomicAdd(&sm.a.cursor[bk[j]], 1u);
            sm.a.bkeys[s] = key[j];
        }
        __syncthreads();

        // in-bin rank (ranks unique: idx in low bits)
        #pragma unroll
        for (int j = 0; j < 4; ++j) {
            int lo = (int)sm.a.binstart[bk[j]], hi = (int)sm.a.binstart[bk[j] + 1];
            int r = lo;
            for (int p = lo; p < hi; ++p) r += (sm.a.bkeys[p] < key[j]) ? 1 : 0;
            sm.a.skeys[r] = key[j];
        }
        __syncthreads();

        // unpack + run heads + outputs to global
        #pragma unroll
        for (int j = 0; j < 4; ++j) {
            int p = j * 256 + t;
            u64 kp = sm.a.skeys[p];
            u32 vb = (u32)(kp >> 32);
            int p0 = p;
            while (p0 > 0 && (u32)(sm.a.skeys[p0 - 1] >> 32) == vb) --p0;  // rare
            int head = (int)(sm.a.skeys[p0] & 1023u);
            u32 u = (vb & 0x80000000u) ? (vb & 0x7FFFFFFFu) : ~vb;   // unmap
            float sv = __uint_as_float(u);
            sval[dcol * K + p] = sv;
            shead[dcol * K + p] = (u16)head;
            if (p == 0)     { ext[dcol]     = sv; ((int*)ext)[2 * D + dcol] = head; }
            if (p == K - 1) { ext[D + dcol] = sv; ((int*)ext)[3 * D + dcol] = head; }
        }
        binstartG[dcol * 257 + t] = sm.a.binstart[t];
        if (t == 0) {
            binstartG[dcol * 257 + 256] = K;
            meta[dcol * 2 + 0] = vmin;
            meta[dcol * 2 + 1] = scale;
        }
    } else if (bid < D + 256) {
        // ---- transpose x -> xT on otherwise-idle blocks (free) ----
        const int tb = bid - D;        // 0..255
        const int d = tb >> 1;
        const int base = (tb & 1) * 2048;
        #pragma unroll
        for (int j = 0; j < 8; ++j) {
            int b = base + j * 256 + t;
            xT[(size_t)d * NB + b] = x[(size_t)b * D + d];   // write coalesced
        }
    }

    grid.sync();

    // ======================= Phase B: search =============================
    {
        const int col = bid & (D - 1);
        const int chunk = bid >> 7;    // 0..3
        ((float4*)sm.b.svs)[t] = ((const float4*)(sval + col * K))[t];
        ((uint2*)sm.b.shs)[t]  = ((const uint2*)(shead + col * K))[t];
        sm.b.binstart[t] = binstartG[col * 257 + t];
        if (t == 0) sm.b.binstart[256] = binstartG[col * 257 + 256];
        const float vmin = meta[col * 2 + 0];
        const float scale = meta[col * 2 + 1];
        __syncthreads();

        #pragma unroll
        for (int j = 0; j < 4; ++j) {
            const int b = chunk * 1024 + j * 256 + t;
            const float xv = xT[(size_t)col * NB + b];        // coalesced
            const int bx = vbin(xv, vmin, scale);
            int lo = (int)sm.b.binstart[bx], hi = (int)sm.b.binstart[bx + 1];
            while (lo < hi) {                 // first pos with svs[pos] > xv
                int mid = (lo + hi) >> 1;
                if (sm.b.svs[mid] <= xv) lo = mid + 1; else hi = mid;
            }
            const int p1 = lo - 1, p2 = lo;
            const int c1 = p1 < 0 ? 0 : p1;
            const int c2 = p2 > K - 1 ? K - 1 : p2;
            float vv1 = sm.b.svs[c1], vv2 = sm.b.svs[c2];
            int h1 = sm.b.shs[c1], h2 = sm.b.shs[c2];
            float d1 = xv - vv1, d2 = xv - vv2;
            float s1 = d1 * d1, s2 = d2 * d2;
            if (p1 < 0) s1 = 3.4e38f;
            if (p2 > K - 1) s2 = 3.4e38f;
            int idx;
            if (s1 < s2) idx = h1;
            else if (s2 < s1) idx = h2;
            else idx = h1 < h2 ? h1 : h2;     // sq tie -> smaller original index
            iminT[(size_t)col * NB + b] = (u16)idx;           // coalesced
        }
    }

    grid.sync();

    // ======================= Phase C: mode + loss (verified) =============
    {
        const int b0 = bid * BB;
        ((float4*)sm.c.xs)[t] = ((const float4*)(x + (size_t)b0 * D))[t];
        {
            uint4 z = make_uint4(0u, 0u, 0u, 0u);
            uint4* a4 = (uint4*)sm.c.cntA;
            uint4* b4 = (uint4*)sm.c.cntB;
            #pragma unroll
            for (int j = 0; j < 2; ++j) { a4[t + 256 * j] = z; b4[t + 256 * j] = z; }
        }
        __syncthreads();

        {   // idx_min counts from iminT
            const int dd = t >> 1, half = t & 1;
            uint2 w = *(const uint2*)(iminT + (size_t)dd * NB + b0 + half * 4);
            int i0 = (int)(w.x & 0xFFFFu), i1 = (int)(w.x >> 16);
            int i2 = (int)(w.y & 0xFFFFu), i3 = (int)(w.y >> 16);
            const int rr = half * 4;
            atomicAdd(&sm.c.cntA[((rr + 0) << 8) + (i0 >> 2)], 1u << ((i0 & 3) * 8));
            atomicAdd(&sm.c.cntA[((rr + 1) << 8) + (i1 >> 2)], 1u << ((i1 & 3) * 8));
            atomicAdd(&sm.c.cntA[((rr + 2) << 8) + (i2 >> 2)], 1u << ((i2 & 3) * 8));
            atomicAdd(&sm.c.cntA[((rr + 3) << 8) + (i3 >> 2)], 1u << ((i3 & 3) * 8));
        }

        const int d = t & (D - 1);
        const int g = t >> 7;
        {   // idx_max from column extremes (reference rounding)
            float cminv = ext[d], cmaxv = ext[D + d];
            int cmini = ((const int*)ext)[2 * D + d];
            int cmaxi = ((const int*)ext)[3 * D + d];
            #pragma unroll
            for (int r = 0; r < 4; ++r) {
                float xv = sm.c.xs[(g * 4 + r) * D + d];
                float d1 = xv - cminv;
                float d2 = xv - cmaxv;
                float s1 = d1 * d1, s2 = d2 * d2;
                int idx;
                if (s1 > s2) idx = cmini;
                else if (s2 > s1) idx = cmaxi;
                else idx = (cmini < cmaxi) ? cmini : cmaxi;
                const int rr = g * 4 + r;
                atomicAdd(&sm.c.cntB[(rr << 8) + (idx >> 2)], 1u << ((idx & 3) * 8));
            }
        }
        __syncthreads();

        const int row = t >> 5;
        const int lane = t & 31;
        {   // mode scan (both buffers at once)
            u32 bkeyA = 0u, bkeyB = 0u;
            #pragma unroll
            for (int j = 0; j < 8; ++j) {
                const int w = j * 32 + lane;
                u32 wA = sm.c.cntA[(row << 8) + w];
                u32 wB = sm.c.cntB[(row << 8) + w];
                #pragma unroll
                for (int sub = 0; sub < 4; ++sub) {
                    const u32 idx = (u32)(w * 4 + sub);
                    u32 cA = (wA >> (sub * 8)) & 0xFFu;
                    u32 cB = (wB >> (sub * 8)) & 0xFFu;
                    u32 kA = (cA << 10) | (1023u - idx);
                    u32 kB = (cB << 10) | (1023u - idx);
                    bkeyA = kA > bkeyA ? kA : bkeyA;
                    bkeyB = kB > bkeyB ? kB : bkeyB;
                }
            }
            #pragma unroll
            for (int m = 16; m >= 1; m >>= 1) {
                u32 oA = __shfl_xor(bkeyA, m);
                u32 oB = __shfl_xor(bkeyB, m);
                bkeyA = oA > bkeyA ? oA : bkeyA;
                bkeyB = oB > bkeyB ? oB : bkeyB;
            }
            if (lane == 0) {
                sm.c.modes[row]      = 1023 - (int)(bkeyA & 1023u);
                sm.c.modes[BB + row] = 1023 - (int)(bkeyB & 1023u);
            }
        }
        __syncthreads();

        {   // triplet distances
            int pm = sm.c.modes[row];
            int nm = sm.c.modes[BB + row];
            const float* pr = cen + (size_t)pm * D;
            const float* nr = cen + (size_t)nm * D;
            float a1 = 0.f, a2 = 0.f, a3 = 0.f;
            #pragma unroll
            for (int j = 0; j < 4; ++j) {
                int dd = j * 32 + lane;
                float xv = sm.c.xs[row * D + dd];
                float pv = pr[dd], nv = nr[dd];
                float e1 = xv - pv + FEPS;
                float e2 = xv - nv + FEPS;
                float e3 = pv - nv + FEPS;
                a1 += e1 * e1; a2 += e2 * e2; a3 += e3 * e3;
            }
            #pragma unroll
            for (int m = 16; m >= 1; m >>= 1) {
                a1 += __shfl_xor(a1, m);
                a2 += __shfl_xor(a2, m);
                a3 += __shfl_xor(a3, m);
            }
            if (lane == 0) {
                float dp = sqrtf(a1);
                float dneg = fminf(sqrtf(a2), sqrtf(a3));
                float term = dp - dneg + 1.0f;
                if (term > 0.f) atomicAdd(out, term * (1.0f / NB));
            }
        }
    }
}

// ===========================================================================
// Tier-1 fallback: verified round-9 two-kernel path (if cooperative launch
// is unsupported). Deterministic branch -> graph-capture safe.
// ===========================================================================
__global__ __launch_bounds__(512) void prep_search_kernel(
    const float* __restrict__ cen, const float* __restrict__ x,
    u16* __restrict__ iminT, float* __restrict__ ext, float* __restrict__ out)
{
    __shared__ u64 bkeys[K];
    __shared__ u64 skeys[K];
    __shared__ float svs[K];
    __shared__ u16 shs[K];
    __shared__ u32 binstart[257];
    __shared__ u32 pfx[256];
    __shared__ u32 cursor[256];
    __shared__ float redmn[8], redmx[8];

    const int dcol = blockIdx.x;
    const int t = threadIdx.x;
    const int wave = t >> 6, lane = t & 63;
    if (dcol == 0 && t == 0) out[0] = 0.0f;

    const float v0 = cen[t * D + dcol];
    const float v1 = cen[(t + 512) * D + dcol];

    float mn = fminf(v0, v1), mx = fmaxf(v0, v1);
    #pragma unroll
    for (int s = 32; s >= 1; s >>= 1) {
        mn = fminf(mn, __shfl_xor(mn, s, 64));
        mx = fmaxf(mx, __shfl_xor(mx, s, 64));
    }
    if (lane == 0) { redmn[wave] = mn; redmx[wave] = mx; }
    if (t < 257) binstart[t] = 0u;
    if (t < 256) cursor[t] = 0u;
    __syncthreads();

    float vmin = redmn[0], vmax = redmx[0];
    #pragma unroll
    for (int w = 1; w < 8; ++w) {
        vmin = fminf(vmin, redmn[w]);
        vmax = fmaxf(vmax, redmx[w]);
    }
    const float range = vmax - vmin;
    const float scale = (range > 0.0f) ? (255.0f / range) : 0.0f;

    u32 u0 = __float_as_uint(v0), u1 = __float_as_uint(v1);
    u0 = (u0 & 0x80000000u) ? ~u0 : (u0 | 0x80000000u);
    u1 = (u1 & 0x80000000u) ? ~u1 : (u1 | 0x80000000u);
    const u64 k0 = ((u64)u0 << 32) | (u32)t;
    const u64 k1 = ((u64)u1 << 32) | (u32)(t + 512);
    const int b0v = vbin(v0, vmin, scale);
    const int b1v = vbin(v1, vmin, scale);
    atomicAdd(&binstart[b0v], 1u);
    atomicAdd(&binstart[b1v], 1u);
    __syncthreads();

    u32 myh = 0u;
    if (t < 256) { myh = binstart[t]; pfx[t] = myh; }
    __syncthreads();
    #pragma unroll
    for (int s = 1; s < 256; s <<= 1) {
        u32 add = 0u;
        if (t < 256 && t >= s) add = pfx[t - s];
        __syncthreads();
        if (t < 256) pfx[t] += add;
        __syncthreads();
    }
    if (t < 256) {
        u32 st = pfx[t] - myh;
        binstart[t] = st;
        cursor[t] = st;
    }
    if (t == 0) binstart[256] = K;
    __syncthreads();

    { u32 s0 = atomicAdd(&cursor[b0v], 1u); bkeys[s0] = k0; }
    { u32 s1 = atomicAdd(&cursor[b1v], 1u); bkeys[s1] = k1; }
    __syncthreads();

    {
        int lo = (int)binstart[b0v], hi = (int)binstart[b0v + 1];
        int r = lo;
        for (int p = lo; p < hi; ++p) r += (bkeys[p] < k0) ? 1 : 0;
        skeys[r] = k0;
    }
    {
        int lo = (int)binstart[b1v], hi = (int)binstart[b1v + 1];
        int r = lo;
        for (int p = lo; p < hi; ++p) r += (bkeys[p] < k1) ? 1 : 0;
        skeys[r] = k1;
    }
    __syncthreads();

    #pragma unroll
    for (int j = 0; j < 2; ++j) {
        int p = j * 512 + t;
        u64 kp = skeys[p];
        u32 vb = (u32)(kp >> 32);
        int p0 = p;
        while (p0 > 0 && (u32)(skeys[p0 - 1] >> 32) == vb) --p0;
        int head = (int)(skeys[p0] & 1023u);
        u32 u = (vb & 0x80000000u) ? (vb & 0x7FFFFFFFu) : ~vb;
        float v = __uint_as_float(u);
        svs[p] = v;
        shs[p] = (u16)head;
        if (p == 0)     { ext[dcol]     = v; ((int*)ext)[2 * D + dcol] = head; }
        if (p == K - 1) { ext[D + dcol] = v; ((int*)ext)[3 * D + dcol] = head; }
    }
    __syncthreads();

    #pragma unroll 1
    for (int ph = 0; ph < 2; ++ph) {
        const int b0 = ph * 2048;
        float xq[4];
        #pragma unroll
        for (int j = 0; j < 4; ++j)
            xq[j] = x[(size_t)(b0 + j * 512 + t) * D + dcol];

        #pragma unroll
        for (int r = 0; r < 4; ++r) {
            const float xv = xq[r];
            const int bx = vbin(xv, vmin, scale);
            int lo = (int)binstart[bx], hi = (int)binstart[bx + 1];
            while (lo < hi) {
                int mid = (lo + hi) >> 1;
                if (svs[mid] <= xv) lo = mid + 1; else hi = mid;
            }
            const int p1 = lo - 1, p2 = lo;
            const int c1 = p1 < 0 ? 0 : p1;
            const int c2 = p2 > K - 1 ? K - 1 : p2;
            float vv1 = svs[c1], vv2 = svs[c2];
            int h1 = shs[c1], h2 = shs[c2];
            float d1 = xv - vv1, d2 = xv - vv2;
            float s1 = d1 * d1, s2 = d2 * d2;
            if (p1 < 0) s1 = 3.4e38f;
            if (p2 > K - 1) s2 = 3.4e38f;
            int idx;
            if (s1 < s2) idx = h1;
            else if (s2 < s1) idx = h2;
            else idx = h1 < h2 ? h1 : h2;
            iminT[(size_t)dcol * NB + b0 + r * 512 + t] = (u16)idx;
        }
    }
}

__global__ __launch_bounds__(256) void mode_loss_kernel(
    const float* __restrict__ x, const float* __restrict__ cen,
    const u16* __restrict__ iminT, const float* __restrict__ ext,
    float* __restrict__ out)
{
    __shared__ float xs[BB * D];
    __shared__ u32 cntA[BB * K / 4];
    __shared__ u32 cntB[BB * K / 4];
    __shared__ int modes[2 * BB];

    const int t = threadIdx.x;
    const int b0 = blockIdx.x * BB;

    ((float4*)xs)[t] = ((const float4*)(x + (size_t)b0 * D))[t];
    {
        uint4 z = make_uint4(0u, 0u, 0u, 0u);
        uint4* a4 = (uint4*)cntA;
        uint4* b4 = (uint4*)cntB;
        #pragma unroll
        for (int j = 0; j < 2; ++j) { a4[t + 256 * j] = z; b4[t + 256 * j] = z; }
    }
    __syncthreads();

    {
        const int dd = t >> 1, half = t & 1;
        uint2 w = *(const uint2*)(iminT + (size_t)dd * NB + b0 + half * 4);
        int i0 = (int)(w.x & 0xFFFFu), i1 = (int)(w.x >> 16);
        int i2 = (int)(w.y & 0xFFFFu), i3 = (int)(w.y >> 16);
        const int rr = half * 4;
        atomicAdd(&cntA[((rr + 0) << 8) + (i0 >> 2)], 1u << ((i0 & 3) * 8));
        atomicAdd(&cntA[((rr + 1) << 8) + (i1 >> 2)], 1u << ((i1 & 3) * 8));
        atomicAdd(&cntA[((rr + 2) << 8) + (i2 >> 2)], 1u << ((i2 & 3) * 8));
        atomicAdd(&cntA[((rr + 3) << 8) + (i3 >> 2)], 1u << ((i3 & 3) * 8));
    }

    const int d = t & (D - 1);
    const int g = t >> 7;
    {
        float cminv = ext[d], cmaxv = ext[D + d];
        int cmini = ((const int*)ext)[2 * D + d];
        int cmaxi = ((const int*)ext)[3 * D + d];
        #pragma unroll
        for (int r = 0; r < 4; ++r) {
            float xv = xs[(g * 4 + r) * D + d];
            float d1 = xv - cminv;
            float d2 = xv - cmaxv;
            float s1 = d1 * d1, s2 = d2 * d2;
            int idx;
            if (s1 > s2) idx = cmini;
            else if (s2 > s1) idx = cmaxi;
            else idx = (cmini < cmaxi) ? cmini : cmaxi;
            const int rr = g * 4 + r;
            atomicAdd(&cntB[(rr << 8) + (idx >> 2)], 1u << ((idx & 3) * 8));
        }
    }
    __syncthreads();

    const int row = t >> 5;
    const int lane = t & 31;
    {
        u32 bkeyA = 0u, bkeyB = 0u;
        #pragma unroll
        for (int j = 0; j < 8; ++j) {
            const int w = j * 32 + lane;
            u32 wA = cntA[(row << 8) + w];
            u32 wB = cntB[(row << 8) + w];
            #pragma unroll
            for (int sub = 0; sub < 4; ++sub) {
                const u32 idx = (u32)(w * 4 + sub);
                u32 cA = (wA >> (sub * 8)) & 0xFFu;
                u32 cB = (wB >> (sub * 8)) & 0xFFu;
                u32 kA = (cA << 10) | (1023u - idx);
                u32 kB = (cB << 10) | (1023u - idx);
                bkeyA = kA > bkeyA ? kA : bkeyA;
                bkeyB = kB > bkeyB ? kB : bkeyB;
            }
        }
        #pragma unroll
        for (int m = 16; m >= 1; m >>= 1) {
            u32 oA = __shfl_xor(bkeyA, m);
            u32 oB = __shfl_xor(bkeyB, m);
            bkeyA = oA > bkeyA ? oA : bkeyA;
            bkeyB = oB > bkeyB ? oB : bkeyB;
        }
        if (lane == 0) {
            modes[row]      = 1023 - (int)(bkeyA & 1023u);
            modes[BB + row] = 1023 - (int)(bkeyB & 1023u);
        }
    }
    __syncthreads();

    {
        int pm = modes[row];
        int nm = modes[BB + row];
        const float* pr = cen + (size_t)pm * D;
        const float* nr = cen + (size_t)nm * D;
        float a1 = 0.f, a2 = 0.f, a3 = 0.f;
        #pragma unroll
        for (int j = 0; j < 4; ++j) {
            int dd = j * 32 + lane;
            float xv = xs[row * D + dd];
            float pv = pr[dd], nv = nr[dd];
            float e1 = xv - pv + FEPS;
            float e2 = xv - nv + FEPS;
            float e3 = pv - nv + FEPS;
            a1 += e1 * e1; a2 += e2 * e2; a3 += e3 * e3;
        }
        #pragma unroll
        for (int m = 16; m >= 1; m >>= 1) {
            a1 += __shfl_xor(a1, m);
            a2 += __shfl_xor(a2, m);
            a3 += __shfl_xor(a3, m);
        }
        if (lane == 0) {
            float dp = sqrtf(a1);
            float dneg = fminf(sqrtf(a2), sqrtf(a3));
            float term = dp - dneg + 1.0f;
            if (term > 0.f) atomicAdd(out, term * (1.0f / NB));
        }
    }
}

extern "C" void kernel_launch(void* const* d_in, const int* in_sizes, int n_in,
                              void* d_out, int out_size, void* d_ws, size_t ws_size,
                              hipStream_t stream) {
    (void)in_sizes; (void)n_in; (void)out_size;
    const float* x   = (const float*)d_in[0];   // [4096,128] f32
    const float* cen = (const float*)d_in[1];   // [1024,128] f32
    float* out = (float*)d_out;                 // scalar f32

    char* ws = (char*)d_ws;
    float* sval      = (float*)(ws + 0);
    float* xT        = (float*)(ws + 524288);
    float* ext       = (float*)(ws + 2621440);
    float* meta      = (float*)(ws + 2623488);
    u32*   binstartG = (u32*)  (ws + 2624512);
    u16*   shead     = (u16*)  (ws + 2756096);
    u16*   iminT     = (u16*)  (ws + 3018240);
    const size_t need = 3018240 + (size_t)D * NB * 2;   // 4,066,816 B

    if (ws_size >= need) {
        const float* cen_a = cen; const float* x_a = x; float* out_a = out;
        void* args[] = { (void*)&cen_a, (void*)&x_a, (void*)&sval, (void*)&shead,
                         (void*)&binstartG, (void*)&meta, (void*)&ext, (void*)&xT,
                         (void*)&iminT, (void*)&out_a };
        hipError_t e = hipLaunchCooperativeKernel(
            (const void*)fused_kernel, dim3(512), dim3(256), args, 0, stream);
        if (e != hipSuccess) {
            (void)hipGetLastError();   // clear; fall back to verified 2-kernel path
            prep_search_kernel<<<D, 512, 0, stream>>>(cen, x, iminT, ext, out);
            mode_loss_kernel<<<NB / BB, 256, 0, stream>>>(x, cen, iminT, ext, out);
        }
    } else {
        // minimal-ws fallback: verified 2-kernel path needs only iminT+ext;
        // place them at the start of ws.
        u16* iminT2 = (u16*)d_ws;
        float* ext2 = (float*)(iminT2 + (size_t)D * NB);
        prep_search_kernel<<<D, 512, 0, stream>>>(cen, x, iminT2, ext2, out);
        mode_loss_kernel<<<NB / BB, 256, 0, stream>>>(x, cen, iminT2, ext2, out);
    }
}

// Round 11
// 95.519 us; speedup vs baseline: 2.4062x; 2.4062x over previous
//
#include <hip/hip_runtime.h>
#include <cstdint>

#define D 128
#define K 1024
#define NB 4096
#define BB 8     // rows per block in mode/loss kernel
#define FEPS 1e-6f

typedef unsigned long long u64;
typedef unsigned int u32;
typedef unsigned short u16;

// ============================================================================
// ws layout (byte offsets), total 1,969,664 B:
//   sval      @0        [D][K] f32    512KB  sorted column values
//   shead     @524288   [D][K] u16    256KB  run-head original index
//   binstartG @786432   [D][257] u32  128KB  bin starts + sentinel
//   meta      @918016   [D][2] f32    1KB    (vmin, scale) per column
//   ext       @919040   4*D f32/int   2KB    col min/max val + first idx
//   iminT     @921088   [D][NB] u16   1MB    per-(d,b) argmin index
// ============================================================================

// Monotone value->bin map; same formula for keys and queries, so the global
// lower_bound of x provably lies inside bin(x)'s slice.
__device__ __forceinline__ int vbin(float v, float vmin, float scale) {
    float fb = (v - vmin) * scale;
    fb = fminf(fmaxf(fb, 0.0f), 255.0f);
    return (int)fb;
}

// ---------------------------------------------------------------------------
// K1: per-column bin-rank sort (verified round-9 semantics), results to global.
// 128 blocks x 512 threads. Sort only — search moved to its own full-machine
// kernel (round 9 fused both into 128 blocks: search ran at half occupancy,
// ~35us; round 10's coop fusion hit grid.sync cost, 167us).
// ---------------------------------------------------------------------------
__global__ __launch_bounds__(512) void prep_kernel(
    const float* __restrict__ cen, float* __restrict__ sval,
    u16* __restrict__ shead, u32* __restrict__ binstartG,
    float* __restrict__ meta, float* __restrict__ ext, float* __restrict__ out)
{
    __shared__ u64 bkeys[K];
    __shared__ u64 skeys[K];
    __shared__ u32 binstart[257];
    __shared__ u32 pfx[256];
    __shared__ u32 cursor[256];
    __shared__ float redmn[8], redmx[8];

    const int dcol = blockIdx.x;
    const int t = threadIdx.x;
    const int wave = t >> 6, lane = t & 63;
    if (dcol == 0 && t == 0) out[0] = 0.0f;   // replaces memset dispatch

    const float v0 = cen[t * D + dcol];
    const float v1 = cen[(t + 512) * D + dcol];

    float mn = fminf(v0, v1), mx = fmaxf(v0, v1);
    #pragma unroll
    for (int s = 32; s >= 1; s >>= 1) {
        mn = fminf(mn, __shfl_xor(mn, s, 64));
        mx = fmaxf(mx, __shfl_xor(mx, s, 64));
    }
    if (lane == 0) { redmn[wave] = mn; redmx[wave] = mx; }
    if (t < 257) binstart[t] = 0u;
    if (t < 256) cursor[t] = 0u;
    __syncthreads();

    float vmin = redmn[0], vmax = redmx[0];
    #pragma unroll
    for (int w = 1; w < 8; ++w) {
        vmin = fminf(vmin, redmn[w]);
        vmax = fmaxf(vmax, redmx[w]);
    }
    const float range = vmax - vmin;
    const float scale = (range > 0.0f) ? (255.0f / range) : 0.0f;

    u32 u0 = __float_as_uint(v0), u1 = __float_as_uint(v1);
    u0 = (u0 & 0x80000000u) ? ~u0 : (u0 | 0x80000000u);   // monotone bit map
    u1 = (u1 & 0x80000000u) ? ~u1 : (u1 | 0x80000000u);
    const u64 k0 = ((u64)u0 << 32) | (u32)t;
    const u64 k1 = ((u64)u1 << 32) | (u32)(t + 512);
    const int b0v = vbin(v0, vmin, scale);
    const int b1v = vbin(v1, vmin, scale);
    atomicAdd(&binstart[b0v], 1u);
    atomicAdd(&binstart[b1v], 1u);
    __syncthreads();

    // exclusive prefix over 256 bins (Hillis-Steele on inclusive)
    u32 myh = 0u;
    if (t < 256) { myh = binstart[t]; pfx[t] = myh; }
    __syncthreads();
    #pragma unroll
    for (int s = 1; s < 256; s <<= 1) {
        u32 add = 0u;
        if (t < 256 && t >= s) add = pfx[t - s];
        __syncthreads();
        if (t < 256) pfx[t] += add;
        __syncthreads();
    }
    if (t < 256) {
        u32 st = pfx[t] - myh;
        binstart[t] = st;
        cursor[t] = st;
    }
    if (t == 0) binstart[256] = K;
    __syncthreads();

    // scatter by bin
    { u32 s0 = atomicAdd(&cursor[b0v], 1u); bkeys[s0] = k0; }
    { u32 s1 = atomicAdd(&cursor[b1v], 1u); bkeys[s1] = k1; }
    __syncthreads();

    // in-bin rank (ranks unique: idx in low bits)
    {
        int lo = (int)binstart[b0v], hi = (int)binstart[b0v + 1];
        int r = lo;
        for (int p = lo; p < hi; ++p) r += (bkeys[p] < k0) ? 1 : 0;
        skeys[r] = k0;
    }
    {
        int lo = (int)binstart[b1v], hi = (int)binstart[b1v + 1];
        int r = lo;
        for (int p = lo; p < hi; ++p) r += (bkeys[p] < k1) ? 1 : 0;
        skeys[r] = k1;
    }
    __syncthreads();

    // unpack + run heads + outputs to global (verified semantics)
    #pragma unroll
    for (int j = 0; j < 2; ++j) {
        int p = j * 512 + t;
        u64 kp = skeys[p];
        u32 vb = (u32)(kp >> 32);
        int p0 = p;
        while (p0 > 0 && (u32)(skeys[p0 - 1] >> 32) == vb) --p0;   // rare (ties)
        int head = (int)(skeys[p0] & 1023u);
        u32 u = (vb & 0x80000000u) ? (vb & 0x7FFFFFFFu) : ~vb;     // unmap
        float v = __uint_as_float(u);
        sval[dcol * K + p] = v;
        shead[dcol * K + p] = (u16)head;
        if (p == 0)     { ext[dcol]     = v; ((int*)ext)[2 * D + dcol] = head; }
        if (p == K - 1) { ext[D + dcol] = v; ((int*)ext)[3 * D + dcol] = head; }
    }
    if (t < 257) binstartG[dcol * 257 + t] = binstart[t];
    if (t == 0) {
        meta[dcol * 2 + 0] = vmin;
        meta[dcol * 2 + 1] = scale;
    }
}

// ---------------------------------------------------------------------------
// K2: bin-bounded argmin search, full-machine. 1024 blocks = (col, 512-row
// chunk) x 256 threads, 2 rows/thread. Column LDS-resident; ~2-3 LDS probes.
// ---------------------------------------------------------------------------
__global__ __launch_bounds__(256) void search_kernel(
    const float* __restrict__ x, const float* __restrict__ sval,
    const u16* __restrict__ shead, const u32* __restrict__ binstartG,
    const float* __restrict__ meta, u16* __restrict__ iminT)
{
    __shared__ float svs[K];       // 4 KB
    __shared__ u16 shs[K];         // 2 KB
    __shared__ u32 binstart[257];  // 1 KB

    const int col = blockIdx.x & (D - 1);
    const int chunk = blockIdx.x >> 7;     // 0..7
    const int t = threadIdx.x;

    ((float4*)svs)[t] = ((const float4*)(sval + col * K))[t];
    ((uint2*)shs)[t]  = ((const uint2*)(shead + col * K))[t];
    binstart[t] = binstartG[col * 257 + t];
    if (t == 0) binstart[256] = binstartG[col * 257 + 256];
    const float vmin = meta[col * 2 + 0];
    const float scale = meta[col * 2 + 1];
    __syncthreads();

    const int b0 = chunk * 512;
    float xq[2];
    #pragma unroll
    for (int j = 0; j < 2; ++j)
        xq[j] = x[(size_t)(b0 + j * 256 + t) * D + col];   // gather, L2-hit

    #pragma unroll
    for (int j = 0; j < 2; ++j) {
        const float xv = xq[j];
        const int bx = vbin(xv, vmin, scale);
        int lo = (int)binstart[bx], hi = (int)binstart[bx + 1];
        while (lo < hi) {                  // first pos with svs[pos] > xv
            int mid = (lo + hi) >> 1;
            if (svs[mid] <= xv) lo = mid + 1; else hi = mid;
        }
        const int p1 = lo - 1, p2 = lo;
        const int c1 = p1 < 0 ? 0 : p1;
        const int c2 = p2 > K - 1 ? K - 1 : p2;
        float vv1 = svs[c1], vv2 = svs[c2];
        int h1 = shs[c1], h2 = shs[c2];
        float d1 = xv - vv1, d2 = xv - vv2;
        float s1 = d1 * d1, s2 = d2 * d2;
        if (p1 < 0) s1 = 3.4e38f;
        if (p2 > K - 1) s2 = 3.4e38f;
        int idx;
        if (s1 < s2) idx = h1;
        else if (s2 < s1) idx = h2;
        else idx = h1 < h2 ? h1 : h2;      // sq tie -> smaller original index
        iminT[(size_t)col * NB + b0 + j * 256 + t] = (u16)idx;   // coalesced
    }
}

// ---------------------------------------------------------------------------
// K3: mode (byte-packed LDS counts) + extremes argmax + triplet loss
// (verified rounds 6-9, unchanged).
// ---------------------------------------------------------------------------
__global__ __launch_bounds__(256) void mode_loss_kernel(
    const float* __restrict__ x, const float* __restrict__ cen,
    const u16* __restrict__ iminT, const float* __restrict__ ext,
    float* __restrict__ out)
{
    __shared__ float xs[BB * D];
    __shared__ u32 cntA[BB * K / 4];
    __shared__ u32 cntB[BB * K / 4];
    __shared__ int modes[2 * BB];

    const int t = threadIdx.x;
    const int b0 = blockIdx.x * BB;

    ((float4*)xs)[t] = ((const float4*)(x + (size_t)b0 * D))[t];
    {
        uint4 z = make_uint4(0u, 0u, 0u, 0u);
        uint4* a4 = (uint4*)cntA;
        uint4* b4 = (uint4*)cntB;
        #pragma unroll
        for (int j = 0; j < 2; ++j) { a4[t + 256 * j] = z; b4[t + 256 * j] = z; }
    }
    __syncthreads();

    {   // idx_min counts from iminT
        const int dd = t >> 1, half = t & 1;
        uint2 w = *(const uint2*)(iminT + (size_t)dd * NB + b0 + half * 4);
        int i0 = (int)(w.x & 0xFFFFu), i1 = (int)(w.x >> 16);
        int i2 = (int)(w.y & 0xFFFFu), i3 = (int)(w.y >> 16);
        const int rr = half * 4;
        atomicAdd(&cntA[((rr + 0) << 8) + (i0 >> 2)], 1u << ((i0 & 3) * 8));
        atomicAdd(&cntA[((rr + 1) << 8) + (i1 >> 2)], 1u << ((i1 & 3) * 8));
        atomicAdd(&cntA[((rr + 2) << 8) + (i2 >> 2)], 1u << ((i2 & 3) * 8));
        atomicAdd(&cntA[((rr + 3) << 8) + (i3 >> 2)], 1u << ((i3 & 3) * 8));
    }

    const int d = t & (D - 1);
    const int g = t >> 7;
    {   // idx_max from column extremes (reference rounding)
        float cminv = ext[d], cmaxv = ext[D + d];
        int cmini = ((const int*)ext)[2 * D + d];
        int cmaxi = ((const int*)ext)[3 * D + d];
        #pragma unroll
        for (int r = 0; r < 4; ++r) {
            float xv = xs[(g * 4 + r) * D + d];
            float d1 = xv - cminv;
            float d2 = xv - cmaxv;
            float s1 = d1 * d1, s2 = d2 * d2;
            int idx;
            if (s1 > s2) idx = cmini;
            else if (s2 > s1) idx = cmaxi;
            else idx = (cmini < cmaxi) ? cmini : cmaxi;
            const int rr = g * 4 + r;
            atomicAdd(&cntB[(rr << 8) + (idx >> 2)], 1u << ((idx & 3) * 8));
        }
    }
    __syncthreads();

    const int row = t >> 5;
    const int lane = t & 31;
    {   // mode scan, both buffers at once
        u32 bkeyA = 0u, bkeyB = 0u;
        #pragma unroll
        for (int j = 0; j < 8; ++j) {
            const int w = j * 32 + lane;
            u32 wA = cntA[(row << 8) + w];
            u32 wB = cntB[(row << 8) + w];
            #pragma unroll
            for (int sub = 0; sub < 4; ++sub) {
                const u32 idx = (u32)(w * 4 + sub);
                u32 cA = (wA >> (sub * 8)) & 0xFFu;
                u32 cB = (wB >> (sub * 8)) & 0xFFu;
                u32 kA = (cA << 10) | (1023u - idx);
                u32 kB = (cB << 10) | (1023u - idx);
                bkeyA = kA > bkeyA ? kA : bkeyA;
                bkeyB = kB > bkeyB ? kB : bkeyB;
            }
        }
        #pragma unroll
        for (int m = 16; m >= 1; m >>= 1) {
            u32 oA = __shfl_xor(bkeyA, m);
            u32 oB = __shfl_xor(bkeyB, m);
            bkeyA = oA > bkeyA ? oA : bkeyA;
            bkeyB = oB > bkeyB ? oB : bkeyB;
        }
        if (lane == 0) {
            modes[row]      = 1023 - (int)(bkeyA & 1023u);
            modes[BB + row] = 1023 - (int)(bkeyB & 1023u);
        }
    }
    __syncthreads();

    {   // triplet distances
        int pm = modes[row];
        int nm = modes[BB + row];
        const float* pr = cen + (size_t)pm * D;
        const float* nr = cen + (size_t)nm * D;
        float a1 = 0.f, a2 = 0.f, a3 = 0.f;
        #pragma unroll
        for (int j = 0; j < 4; ++j) {
            int dd = j * 32 + lane;
            float xv = xs[row * D + dd];
            float pv = pr[dd], nv = nr[dd];
            float e1 = xv - pv + FEPS;
            float e2 = xv - nv + FEPS;
            float e3 = pv - nv + FEPS;
            a1 += e1 * e1; a2 += e2 * e2; a3 += e3 * e3;
        }
        #pragma unroll
        for (int m = 16; m >= 1; m >>= 1) {
            a1 += __shfl_xor(a1, m);
            a2 += __shfl_xor(a2, m);
            a3 += __shfl_xor(a3, m);
        }
        if (lane == 0) {
            float dp = sqrtf(a1);
            float dneg = fminf(sqrtf(a2), sqrtf(a3));
            float term = dp - dneg + 1.0f;
            if (term > 0.f) atomicAdd(out, term * (1.0f / NB));
        }
    }
}

extern "C" void kernel_launch(void* const* d_in, const int* in_sizes, int n_in,
                              void* d_out, int out_size, void* d_ws, size_t ws_size,
                              hipStream_t stream) {
    (void)in_sizes; (void)n_in; (void)out_size; (void)ws_size;
    const float* x   = (const float*)d_in[0];   // [4096,128] f32
    const float* cen = (const float*)d_in[1];   // [1024,128] f32
    float* out = (float*)d_out;                 // scalar f32

    char* ws = (char*)d_ws;
    float* sval      = (float*)(ws + 0);
    u16*   shead     = (u16*)  (ws + 524288);
    u32*   binstartG = (u32*)  (ws + 786432);
    float* meta      = (float*)(ws + 918016);
    float* ext       = (float*)(ws + 919040);
    u16*   iminT     = (u16*)  (ws + 921088);
    // need = 1,969,664 B; harness ws is far larger (it 0xAA-fills 256MB).

    prep_kernel<<<D, 512, 0, stream>>>(cen, sval, shead, binstartG, meta, ext, out);
    search_kernel<<<D * 8, 256, 0, stream>>>(x, sval, shead, binstartG, meta, iminT);
    mode_loss_kernel<<<NB / BB, 256, 0, stream>>>(x, cen, iminT, ext, out);
}

// Round 12
// 95.204 us; speedup vs baseline: 2.4141x; 1.0033x over previous
//
#include <hip/hip_runtime.h>
#include <cstdint>

#define D 128
#define K 1024
#define NB 4096
#define BB 8     // rows per block in mode/loss kernel
#define FEPS 1e-6f

typedef unsigned long long u64;
typedef unsigned int u32;
typedef unsigned short u16;

// ============================================================================
// ws layout (byte offsets), total 2,493,952 B:
//   sval      @0        [D][K] f32    512KB  sorted column values
//   shead     @524288   [D][K] u16    256KB  run-head original index
//   binstartG @786432   [D][257] u32  ~128KB bin starts + sentinel
//   meta      @918016   [D][2] f32    1KB    (vmin, scale) per column
//   ext       @919040   4*D f32/int   2KB    col min/max val + first idx
//   iminT     @921088   [D][NB] u16   1MB    per-(d,b) argmin index
//   cenT      @1969664  [D][K] f32    512KB  transposed centroids
// ============================================================================

// Monotone value->bin map; same formula for keys and queries, so the global
// lower_bound of x provably lies inside bin(x)'s slice.
__device__ __forceinline__ int vbin(float v, float vmin, float scale) {
    float fb = (v - vmin) * scale;
    fb = fminf(fmaxf(fb, 0.0f), 255.0f);
    return (int)fb;
}

// ---------------------------------------------------------------------------
// K0: transpose cen [K][D] -> cenT [D][K]. Full machine, divergent reads are
// latency-hidden at 256 blocks; writes coalesced. Removes prep's 64-line
// column gather.
// ---------------------------------------------------------------------------
__global__ __launch_bounds__(256) void transpose_cen_kernel(
    const float* __restrict__ cen, float* __restrict__ cenT)
{
    const int d = blockIdx.x >> 1;
    const int k0 = (blockIdx.x & 1) * 512;
    const int t = threadIdx.x;
    #pragma unroll
    for (int j = 0; j < 2; ++j) {
        int k = k0 + j * 256 + t;
        cenT[d * K + k] = cen[k * D + d];
    }
}

// ---------------------------------------------------------------------------
// K1: per-column bin-rank sort — 5 barriers (was ~22). At 1 block/CU every
// barrier-separated phase's latency is fully exposed; R11's 16-barrier
// Hillis-Steele prefix is replaced by a single-wave shfl_up scan.
// Sort semantics identical to verified R9/R11 (same bin formula, key map,
// in-bin rank, run heads).
// ---------------------------------------------------------------------------
__global__ __launch_bounds__(512) void prep_kernel(
    const float* __restrict__ cenT, float* __restrict__ sval,
    u16* __restrict__ shead, u32* __restrict__ binstartG,
    float* __restrict__ meta, float* __restrict__ ext, float* __restrict__ out)
{
    __shared__ u64 bkeys[K];        // 8 KB keys scattered by bin
    __shared__ u64 skeys[K];        // 8 KB sorted keys
    __shared__ u32 binstart[257];   // histogram, then exclusive starts
    __shared__ u32 cursor[256];
    __shared__ float redmn[8], redmx[8];

    const int dcol = blockIdx.x;
    const int t = threadIdx.x;
    const int wave = t >> 6, lane = t & 63;
    if (dcol == 0 && t == 0) out[0] = 0.0f;   // replaces memset dispatch

    // coalesced column load from cenT
    const float v0 = cenT[dcol * K + t];
    const float v1 = cenT[dcol * K + 512 + t];

    // wave min/max + hist zero under ONE barrier
    float mn = fminf(v0, v1), mx = fmaxf(v0, v1);
    #pragma unroll
    for (int s = 32; s >= 1; s >>= 1) {
        mn = fminf(mn, __shfl_xor(mn, s, 64));
        mx = fmaxf(mx, __shfl_xor(mx, s, 64));
    }
    if (lane == 0) { redmn[wave] = mn; redmx[wave] = mx; }
    if (t < 257) binstart[t] = 0u;
    __syncthreads();                                       // barrier 1

    float vmin = redmn[0], vmax = redmx[0];
    #pragma unroll
    for (int w = 1; w < 8; ++w) {
        vmin = fminf(vmin, redmn[w]);
        vmax = fmaxf(vmax, redmx[w]);
    }
    const float range = vmax - vmin;
    const float scale = (range > 0.0f) ? (255.0f / range) : 0.0f;

    u32 u0 = __float_as_uint(v0), u1 = __float_as_uint(v1);
    u0 = (u0 & 0x80000000u) ? ~u0 : (u0 | 0x80000000u);    // monotone bit map
    u1 = (u1 & 0x80000000u) ? ~u1 : (u1 | 0x80000000u);
    const u64 k0 = ((u64)u0 << 32) | (u32)t;
    const u64 k1 = ((u64)u1 << 32) | (u32)(t + 512);
    const int b0v = vbin(v0, vmin, scale);
    const int b1v = vbin(v1, vmin, scale);
    atomicAdd(&binstart[b0v], 1u);
    atomicAdd(&binstart[b1v], 1u);
    __syncthreads();                                       // barrier 2

    // single-wave exclusive prefix over 256 bins (4 bins/lane, shfl_up scan)
    if (wave == 0) {
        u32 h[4]; u32 s = 0u;
        #pragma unroll
        for (int i = 0; i < 4; ++i) { h[i] = binstart[lane * 4 + i]; s += h[i]; }
        u32 inc = s;
        #pragma unroll
        for (int off = 1; off < 64; off <<= 1) {
            u32 n = __shfl_up(inc, off, 64);
            if (lane >= off) inc += n;
        }
        u32 run = inc - s;                 // exclusive start of this lane's 4
        #pragma unroll
        for (int i = 0; i < 4; ++i) {
            binstart[lane * 4 + i] = run;  // lockstep: all h[] loads precede stores
            cursor[lane * 4 + i] = run;
            run += h[i];
        }
        if (lane == 63) binstart[256] = K;
    }
    __syncthreads();                                       // barrier 3

    // scatter by bin
    { u32 s0 = atomicAdd(&cursor[b0v], 1u); bkeys[s0] = k0; }
    { u32 s1 = atomicAdd(&cursor[b1v], 1u); bkeys[s1] = k1; }
    __syncthreads();                                       // barrier 4

    // in-bin rank (ranks unique: idx in low bits)
    {
        int lo = (int)binstart[b0v], hi = (int)binstart[b0v + 1];
        int r = lo;
        for (int p = lo; p < hi; ++p) r += (bkeys[p] < k0) ? 1 : 0;
        skeys[r] = k0;
    }
    {
        int lo = (int)binstart[b1v], hi = (int)binstart[b1v + 1];
        int r = lo;
        for (int p = lo; p < hi; ++p) r += (bkeys[p] < k1) ? 1 : 0;
        skeys[r] = k1;
    }
    __syncthreads();                                       // barrier 5

    // unpack + run heads + outputs (verified semantics)
    #pragma unroll
    for (int j = 0; j < 2; ++j) {
        int p = j * 512 + t;
        u64 kp = skeys[p];
        u32 vb = (u32)(kp >> 32);
        int p0 = p;
        while (p0 > 0 && (u32)(skeys[p0 - 1] >> 32) == vb) --p0;   // rare (ties)
        int head = (int)(skeys[p0] & 1023u);
        u32 u = (vb & 0x80000000u) ? (vb & 0x7FFFFFFFu) : ~vb;     // unmap
        float v = __uint_as_float(u);
        sval[dcol * K + p] = v;
        shead[dcol * K + p] = (u16)head;
        if (p == 0)     { ext[dcol]     = v; ((int*)ext)[2 * D + dcol] = head; }
        if (p == K - 1) { ext[D + dcol] = v; ((int*)ext)[3 * D + dcol] = head; }
    }
    if (t < 257) binstartG[dcol * 257 + t] = binstart[t];
    if (t == 0) {
        meta[dcol * 2 + 0] = vmin;
        meta[dcol * 2 + 1] = scale;
    }
}

// ---------------------------------------------------------------------------
// K2: bin-bounded argmin search (verified R11, unchanged). 1024 blocks.
// ---------------------------------------------------------------------------
__global__ __launch_bounds__(256) void search_kernel(
    const float* __restrict__ x, const float* __restrict__ sval,
    const u16* __restrict__ shead, const u32* __restrict__ binstartG,
    const float* __restrict__ meta, u16* __restrict__ iminT)
{
    __shared__ float svs[K];       // 4 KB
    __shared__ u16 shs[K];         // 2 KB
    __shared__ u32 binstart[257];  // 1 KB

    const int col = blockIdx.x & (D - 1);
    const int chunk = blockIdx.x >> 7;     // 0..7
    const int t = threadIdx.x;

    ((float4*)svs)[t] = ((const float4*)(sval + col * K))[t];
    ((uint2*)shs)[t]  = ((const uint2*)(shead + col * K))[t];
    binstart[t] = binstartG[col * 257 + t];
    if (t == 0) binstart[256] = binstartG[col * 257 + 256];
    const float vmin = meta[col * 2 + 0];
    const float scale = meta[col * 2 + 1];
    __syncthreads();

    const int b0 = chunk * 512;
    float xq[2];
    #pragma unroll
    for (int j = 0; j < 2; ++j)
        xq[j] = x[(size_t)(b0 + j * 256 + t) * D + col];   // gather, L2-hit

    #pragma unroll
    for (int j = 0; j < 2; ++j) {
        const float xv = xq[j];
        const int bx = vbin(xv, vmin, scale);
        int lo = (int)binstart[bx], hi = (int)binstart[bx + 1];
        while (lo < hi) {                  // first pos with svs[pos] > xv
            int mid = (lo + hi) >> 1;
            if (svs[mid] <= xv) lo = mid + 1; else hi = mid;
        }
        const int p1 = lo - 1, p2 = lo;
        const int c1 = p1 < 0 ? 0 : p1;
        const int c2 = p2 > K - 1 ? K - 1 : p2;
        float vv1 = svs[c1], vv2 = svs[c2];
        int h1 = shs[c1], h2 = shs[c2];
        float d1 = xv - vv1, d2 = xv - vv2;
        float s1 = d1 * d1, s2 = d2 * d2;
        if (p1 < 0) s1 = 3.4e38f;
        if (p2 > K - 1) s2 = 3.4e38f;
        int idx;
        if (s1 < s2) idx = h1;
        else if (s2 < s1) idx = h2;
        else idx = h1 < h2 ? h1 : h2;      // sq tie -> smaller original index
        iminT[(size_t)col * NB + b0 + j * 256 + t] = (u16)idx;   // coalesced
    }
}

// ---------------------------------------------------------------------------
// K3: mode (byte-packed LDS counts) + extremes argmax + triplet loss
// (verified rounds 6-11, unchanged).
// ---------------------------------------------------------------------------
__global__ __launch_bounds__(256) void mode_loss_kernel(
    const float* __restrict__ x, const float* __restrict__ cen,
    const u16* __restrict__ iminT, const float* __restrict__ ext,
    float* __restrict__ out)
{
    __shared__ float xs[BB * D];
    __shared__ u32 cntA[BB * K / 4];
    __shared__ u32 cntB[BB * K / 4];
    __shared__ int modes[2 * BB];

    const int t = threadIdx.x;
    const int b0 = blockIdx.x * BB;

    ((float4*)xs)[t] = ((const float4*)(x + (size_t)b0 * D))[t];
    {
        uint4 z = make_uint4(0u, 0u, 0u, 0u);
        uint4* a4 = (uint4*)cntA;
        uint4* b4 = (uint4*)cntB;
        #pragma unroll
        for (int j = 0; j < 2; ++j) { a4[t + 256 * j] = z; b4[t + 256 * j] = z; }
    }
    __syncthreads();

    {   // idx_min counts from iminT
        const int dd = t >> 1, half = t & 1;
        uint2 w = *(const uint2*)(iminT + (size_t)dd * NB + b0 + half * 4);
        int i0 = (int)(w.x & 0xFFFFu), i1 = (int)(w.x >> 16);
        int i2 = (int)(w.y & 0xFFFFu), i3 = (int)(w.y >> 16);
        const int rr = half * 4;
        atomicAdd(&cntA[((rr + 0) << 8) + (i0 >> 2)], 1u << ((i0 & 3) * 8));
        atomicAdd(&cntA[((rr + 1) << 8) + (i1 >> 2)], 1u << ((i1 & 3) * 8));
        atomicAdd(&cntA[((rr + 2) << 8) + (i2 >> 2)], 1u << ((i2 & 3) * 8));
        atomicAdd(&cntA[((rr + 3) << 8) + (i3 >> 2)], 1u << ((i3 & 3) * 8));
    }

    const int d = t & (D - 1);
    const int g = t >> 7;
    {   // idx_max from column extremes (reference rounding)
        float cminv = ext[d], cmaxv = ext[D + d];
        int cmini = ((const int*)ext)[2 * D + d];
        int cmaxi = ((const int*)ext)[3 * D + d];
        #pragma unroll
        for (int r = 0; r < 4; ++r) {
            float xv = xs[(g * 4 + r) * D + d];
            float d1 = xv - cminv;
            float d2 = xv - cmaxv;
            float s1 = d1 * d1, s2 = d2 * d2;
            int idx;
            if (s1 > s2) idx = cmini;
            else if (s2 > s1) idx = cmaxi;
            else idx = (cmini < cmaxi) ? cmini : cmaxi;
            const int rr = g * 4 + r;
            atomicAdd(&cntB[(rr << 8) + (idx >> 2)], 1u << ((idx & 3) * 8));
        }
    }
    __syncthreads();

    const int row = t >> 5;
    const int lane = t & 31;
    {   // mode scan, both buffers at once
        u32 bkeyA = 0u, bkeyB = 0u;
        #pragma unroll
        for (int j = 0; j < 8; ++j) {
            const int w = j * 32 + lane;
            u32 wA = cntA[(row << 8) + w];
            u32 wB = cntB[(row << 8) + w];
            #pragma unroll
            for (int sub = 0; sub < 4; ++sub) {
                const u32 idx = (u32)(w * 4 + sub);
                u32 cA = (wA >> (sub * 8)) & 0xFFu;
                u32 cB = (wB >> (sub * 8)) & 0xFFu;
                u32 kA = (cA << 10) | (1023u - idx);
                u32 kB = (cB << 10) | (1023u - idx);
                bkeyA = kA > bkeyA ? kA : bkeyA;
                bkeyB = kB > bkeyB ? kB : bkeyB;
            }
        }
        #pragma unroll
        for (int m = 16; m >= 1; m >>= 1) {
            u32 oA = __shfl_xor(bkeyA, m);
            u32 oB = __shfl_xor(bkeyB, m);
            bkeyA = oA > bkeyA ? oA : bkeyA;
            bkeyB = oB > bkeyB ? oB : bkeyB;
        }
        if (lane == 0) {
            modes[row]      = 1023 - (int)(bkeyA & 1023u);
            modes[BB + row] = 1023 - (int)(bkeyB & 1023u);
        }
    }
    __syncthreads();

    {   // triplet distances
        int pm = modes[row];
        int nm = modes[BB + row];
        const float* pr = cen + (size_t)pm * D;
        const float* nr = cen + (size_t)nm * D;
        float a1 = 0.f, a2 = 0.f, a3 = 0.f;
        #pragma unroll
        for (int j = 0; j < 4; ++j) {
            int dd = j * 32 + lane;
            float xv = xs[row * D + dd];
            float pv = pr[dd], nv = nr[dd];
            float e1 = xv - pv + FEPS;
            float e2 = xv - nv + FEPS;
            float e3 = pv - nv + FEPS;
            a1 += e1 * e1; a2 += e2 * e2; a3 += e3 * e3;
        }
        #pragma unroll
        for (int m = 16; m >= 1; m >>= 1) {
            a1 += __shfl_xor(a1, m);
            a2 += __shfl_xor(a2, m);
            a3 += __shfl_xor(a3, m);
        }
        if (lane == 0) {
            float dp = sqrtf(a1);
            float dneg = fminf(sqrtf(a2), sqrtf(a3));
            float term = dp - dneg + 1.0f;
            if (term > 0.f) atomicAdd(out, term * (1.0f / NB));
        }
    }
}

extern "C" void kernel_launch(void* const* d_in, const int* in_sizes, int n_in,
                              void* d_out, int out_size, void* d_ws, size_t ws_size,
                              hipStream_t stream) {
    (void)in_sizes; (void)n_in; (void)out_size; (void)ws_size;
    const float* x   = (const float*)d_in[0];   // [4096,128] f32
    const float* cen = (const float*)d_in[1];   // [1024,128] f32
    float* out = (float*)d_out;                 // scalar f32

    char* ws = (char*)d_ws;
    float* sval      = (float*)(ws + 0);
    u16*   shead     = (u16*)  (ws + 524288);
    u32*   binstartG = (u32*)  (ws + 786432);
    float* meta      = (float*)(ws + 918016);
    float* ext       = (float*)(ws + 919040);
    u16*   iminT     = (u16*)  (ws + 921088);
    float* cenT      = (float*)(ws + 1969664);
    // need = 2,493,952 B; harness ws is far larger.

    transpose_cen_kernel<<<2 * D, 256, 0, stream>>>(cen, cenT);
    prep_kernel<<<D, 512, 0, stream>>>(cenT, sval, shead, binstartG, meta, ext, out);
    search_kernel<<<D * 8, 256, 0, stream>>>(x, sval, shead, binstartG, meta, iminT);
    mode_loss_kernel<<<NB / BB, 256, 0, stream>>>(x, cen, iminT, ext, out);
}